// Round 1
// baseline (212.484 us; speedup 1.0000x reference)
//
#include <hip/hip_runtime.h>

// HyperedgeMaxAggregator: out[s, :] = max over members j with segment_ids[j]==s
// of emb_table[node_idx[j], :]; empty segments -> 0.
//
// segment_ids is SORTED, so each segment is a contiguous slice of the flat
// membership arrays. One wave (64 lanes) per segment; lane L owns features
// [2L, 2L+1] as a float2 (64 lanes x 8 B = 512 B coalesced per member row).
// Segment bounds via uniform binary search over the sorted segment_ids.

#define D_FEAT 128

__global__ __launch_bounds__(64) void hyperedge_max_kernel(
    const float* __restrict__ emb,      // [N_NODES, 128]
    const int* __restrict__ node_idx,   // [FLAT]
    const int* __restrict__ seg_ids,    // [FLAT], sorted
    float* __restrict__ out,            // [num_segments, 128]
    int flat, int num_segments) {

    const int s = blockIdx.x;
    if (s >= num_segments) return;

    // lower_bound(s): first i with seg_ids[i] >= s  (uniform across wave)
    int lo = 0, hi = flat;
    while (lo < hi) {
        int mid = (lo + hi) >> 1;
        if (seg_ids[mid] < s) lo = mid + 1; else hi = mid;
    }
    const int start = lo;
    // lower_bound(s+1), resuming from start
    hi = flat;
    while (lo < hi) {
        int mid = (lo + hi) >> 1;
        if (seg_ids[mid] < s + 1) lo = mid + 1; else hi = mid;
    }
    const int end = lo;

    const int lane = threadIdx.x;  // 0..63

    float2 m = make_float2(-INFINITY, -INFINITY);

    int j = start;
    // 4-wide unroll: 4 independent idx loads + 4 independent row loads in flight
    for (; j + 3 < end; j += 4) {
        int n0 = node_idx[j + 0];
        int n1 = node_idx[j + 1];
        int n2 = node_idx[j + 2];
        int n3 = node_idx[j + 3];
        float2 v0 = ((const float2*)(emb + (size_t)n0 * D_FEAT))[lane];
        float2 v1 = ((const float2*)(emb + (size_t)n1 * D_FEAT))[lane];
        float2 v2 = ((const float2*)(emb + (size_t)n2 * D_FEAT))[lane];
        float2 v3 = ((const float2*)(emb + (size_t)n3 * D_FEAT))[lane];
        m.x = fmaxf(m.x, fmaxf(fmaxf(v0.x, v1.x), fmaxf(v2.x, v3.x)));
        m.y = fmaxf(m.y, fmaxf(fmaxf(v0.y, v1.y), fmaxf(v2.y, v3.y)));
    }
    for (; j < end; ++j) {
        int n = node_idx[j];
        float2 v = ((const float2*)(emb + (size_t)n * D_FEAT))[lane];
        m.x = fmaxf(m.x, v.x);
        m.y = fmaxf(m.y, v.y);
    }

    if (start == end) {  // empty segment -> 0 (matches isfinite fixup)
        m.x = 0.0f;
        m.y = 0.0f;
    }

    ((float2*)(out + (size_t)s * D_FEAT))[lane] = m;
}

extern "C" void kernel_launch(void* const* d_in, const int* in_sizes, int n_in,
                              void* d_out, int out_size, void* d_ws, size_t ws_size,
                              hipStream_t stream) {
    const float* emb      = (const float*)d_in[0];
    const int*   node_idx = (const int*)d_in[1];
    const int*   seg_ids  = (const int*)d_in[2];
    float*       out      = (float*)d_out;

    const int flat         = in_sizes[1];
    const int num_segments = out_size / D_FEAT;

    hyperedge_max_kernel<<<num_segments, 64, 0, stream>>>(
        emb, node_idx, seg_ids, out, flat, num_segments);
}

// Round 2
// 201.605 us; speedup vs baseline: 1.0540x; 1.0540x over previous
//
#include <hip/hip_runtime.h>

// HyperedgeMaxAggregator: out[s, :] = max over members j with segment_ids[j]==s
// of emb_table[node_idx[j], :]; empty segments -> 0.
//
// R2: two-kernel structure.
//  K1: segment start offsets off[s] = lower_bound(seg_ids, s) into d_ws
//      (removes the 2x21 dependent-load binary search from every wave).
//  K2: one wave per segment; member indices fetched 64-at-a-time with ONE
//      coalesced load + __shfl broadcast (idx loads leave the dependence
//      chain); row gathers issued in independent batches of 8 for MLP.
//      Lane L holds features [2L,2L+1] as float2 (512 B coalesced per row).

#define D_FEAT 128

__global__ __launch_bounds__(256) void seg_offsets_kernel(
    const int* __restrict__ seg,  // [flat], sorted
    int* __restrict__ off,        // [nseg+1]
    int flat, int nseg) {
    int j = blockIdx.x * blockDim.x + threadIdx.x;
    if (j >= flat) return;
    int cur = seg[j];
    if (j == 0) {
        for (int s = 0; s <= cur; ++s) off[s] = 0;
    }
    int nxt = (j + 1 < flat) ? seg[j + 1] : nseg;
    for (int s = cur + 1; s <= nxt; ++s) off[s] = j + 1;
}

__global__ __launch_bounds__(64) void hyperedge_max_kernel(
    const float* __restrict__ emb,      // [N_NODES, 128]
    const int* __restrict__ node_idx,   // [FLAT]
    const int* __restrict__ off,        // [nseg+1]
    float* __restrict__ out,            // [nseg, 128]
    int num_segments) {

    const int s = blockIdx.x;
    const int lane = threadIdx.x;  // 0..63

    const int start = off[s];
    const int end   = off[s + 1];

    float2 m = make_float2(-INFINITY, -INFINITY);

    int j = start;
    while (j < end) {
        const int chunk = min(64, end - j);
        // One coalesced load covers up to 64 member indices for the wave.
        int idxv = (lane < chunk) ? node_idx[j + lane] : 0;

        int k = 0;
        for (; k + 8 <= chunk; k += 8) {
            // __shfl broadcasts are VALU-only: all 8 row loads are
            // independent and issue back-to-back before any vmcnt wait.
            const float2* r0 = (const float2*)(emb + (size_t)__shfl(idxv, k + 0) * D_FEAT);
            const float2* r1 = (const float2*)(emb + (size_t)__shfl(idxv, k + 1) * D_FEAT);
            const float2* r2 = (const float2*)(emb + (size_t)__shfl(idxv, k + 2) * D_FEAT);
            const float2* r3 = (const float2*)(emb + (size_t)__shfl(idxv, k + 3) * D_FEAT);
            const float2* r4 = (const float2*)(emb + (size_t)__shfl(idxv, k + 4) * D_FEAT);
            const float2* r5 = (const float2*)(emb + (size_t)__shfl(idxv, k + 5) * D_FEAT);
            const float2* r6 = (const float2*)(emb + (size_t)__shfl(idxv, k + 6) * D_FEAT);
            const float2* r7 = (const float2*)(emb + (size_t)__shfl(idxv, k + 7) * D_FEAT);
            float2 v0 = r0[lane];
            float2 v1 = r1[lane];
            float2 v2 = r2[lane];
            float2 v3 = r3[lane];
            float2 v4 = r4[lane];
            float2 v5 = r5[lane];
            float2 v6 = r6[lane];
            float2 v7 = r7[lane];
            m.x = fmaxf(m.x, fmaxf(fmaxf(fmaxf(v0.x, v1.x), fmaxf(v2.x, v3.x)),
                                   fmaxf(fmaxf(v4.x, v5.x), fmaxf(v6.x, v7.x))));
            m.y = fmaxf(m.y, fmaxf(fmaxf(fmaxf(v0.y, v1.y), fmaxf(v2.y, v3.y)),
                                   fmaxf(fmaxf(v4.y, v5.y), fmaxf(v6.y, v7.y))));
        }
        for (; k < chunk; ++k) {
            const float2* r = (const float2*)(emb + (size_t)__shfl(idxv, k) * D_FEAT);
            float2 v = r[lane];
            m.x = fmaxf(m.x, v.x);
            m.y = fmaxf(m.y, v.y);
        }
        j += chunk;
    }

    if (start == end) {  // empty segment -> 0 (matches isfinite fixup)
        m.x = 0.0f;
        m.y = 0.0f;
    }

    ((float2*)(out + (size_t)s * D_FEAT))[lane] = m;
}

extern "C" void kernel_launch(void* const* d_in, const int* in_sizes, int n_in,
                              void* d_out, int out_size, void* d_ws, size_t ws_size,
                              hipStream_t stream) {
    const float* emb      = (const float*)d_in[0];
    const int*   node_idx = (const int*)d_in[1];
    const int*   seg_ids  = (const int*)d_in[2];
    float*       out      = (float*)d_out;
    int*         off      = (int*)d_ws;   // (num_segments+1) ints

    const int flat         = in_sizes[1];
    const int num_segments = out_size / D_FEAT;

    seg_offsets_kernel<<<(flat + 255) / 256, 256, 0, stream>>>(
        seg_ids, off, flat, num_segments);

    hyperedge_max_kernel<<<num_segments, 64, 0, stream>>>(
        emb, node_idx, off, out, num_segments);
}